// Round 25
// baseline (21.951 us; speedup 1.0000x reference)
//
#include <hip/hip_runtime.h>

// VectorQuantizer on MI355X — v20: v16 + persistent 2-group software pipeline.
// latents: [64, 64, 32, 32] f32, embedding: [512, 64] f32.
// d_out: quantized_st [64,64,32,32] f32 (4194304 elems) then vq_loss scalar f32.
// Math: quantized_st == embedding[argmin d2], vq_loss == 1.25 * mean((q - x)^2).
// Identity: per position, (q-x)^2 summed over d = (winning_score - 2) + ||x||^2,
// score = ||w||^2 + 2 + w.(-2x) = ||w||^2 + 2 - 2 x.w.
//
// v20 vs v16: each block processes TWO groups of 64 positions (same 128 total).
// W-frags built once per block (was per 128-pos group anyway, now amortized
// over 2 k-loops); group-1's x-loads are issued DURING group-0's k-loop and
// staged into a second 8KB LDS buffer before the same barrier — the HBM
// x-load latency hides under MFMA instead of heading the serial chain.
// Lessons kept: no threadfence, no nontemporal, no memset nodes, partial[]
// + 1-block finalize, packed u32 argmin (strict min = jnp tie-break).

#define NUM_EMB 512
#define DIM 64
#define HW 1024
#define TOTAL 4194304
#define FUSED_BLOCKS 512    // 512 threads = 8 waves; 2 groups x 64 pos per block

typedef __attribute__((ext_vector_type(8))) short bf16x8;
typedef __attribute__((ext_vector_type(4))) float f32x4;
typedef __attribute__((ext_vector_type(4))) int   i32x4;

// d_ws layout: [0, 2048) : float partial[512]

__device__ __forceinline__ int cvt_pk_bf16(float lo, float hi) {
    int r;
    asm("v_cvt_pk_bf16_f32 %0, %1, %2" : "=v"(r) : "v"(lo), "v"(hi));
    return r;
}

__device__ __forceinline__ unsigned int umin32(unsigned int a, unsigned int b) {
    return a < b ? a : b;
}

// Wave w owns codes [w*64, w*64+64). Lane l: c=l&15, g=l>>4.
// A-frag af[kt][f]: code kw+kt*16+c, dims f*32+g*8..+7, bf16(w).
// Per group: x in LDS as bf16(-2x): [64 pos][8 chunks of 16B], chunk ch at
// ch^(pos&7); staged by thread t: pos=t&63, chunk t>>6. B-frag for pos-tile
// pt (0..3): row pt*16+c, logical chunk f*4+g -> phys ^(c&7). MFMA D:
// col=lane&15=position, row=g*4+r -> acc[r] = biased score of code
// kw+kt*16+g*4+r.  Packed argmin: u32 = (score_bits & ~511) | k; LDS
// atomicMin combines waves; strict min keeps smallest k on masked-score
// ties (jnp.argmin tie-break).
__global__ __launch_bounds__(512, 4) void fused_vq_kernel(
    const float* __restrict__ latents, const float* __restrict__ emb,
    float* __restrict__ out, float* __restrict__ partial) {
    __shared__ char xl[2][8192];                   // double-buffered bf16(-2x)
    __shared__ unsigned int bestmin[2][64];
    __shared__ float wsum[8];

    const int tid  = threadIdx.x;
    const int wave = tid >> 6;                     // 0..7
    const int l    = tid & 63;
    const int c    = l & 15;
    const int g    = l >> 4;

    const int n0  = blockIdx.x * 128;              // 128 positions, same b row
    const int b   = n0 >> 10;
    const int hw0 = n0 & 1023;

    const int pos = tid & 63;                      // position staged (per group)
    const int ch  = tid >> 6;                      // dim octant (8 dims)
    const int swx = (ch ^ (pos & 7)) << 4;         // staging swizzle byte
    const float* xpb = latents + (size_t)b * (DIM * HW) + hw0 + pos;

    if (tid < 64) { bestmin[0][tid] = 0xFFFFFFFFu; bestmin[1][tid] = 0xFFFFFFFFu; }

    float contrib = 0.f;                           // x^2 + score accumulators

    // ---- group-0 x loads (issued first; latency under W-build) ----
    float xv0[8];
#pragma unroll
    for (int j = 0; j < 8; ++j) xv0[j] = xpb[(ch * 8 + j) * HW];

    // ---- W-frags: built ONCE per block (L3/L2-hot, 16KB per wave) ----
    const int kw = wave * 64;
    bf16x8 af[4][2];
    f32x4  ww4[4];
#pragma unroll
    for (int kt = 0; kt < 4; ++kt) {
        const float* wrow = emb + (kw + kt * 16 + c) * 64;
        const f32x4 w0a = *(const f32x4*)(wrow + g * 8);
        const f32x4 w0b = *(const f32x4*)(wrow + g * 8 + 4);
        const f32x4 w1a = *(const f32x4*)(wrow + 32 + g * 8);
        const f32x4 w1b = *(const f32x4*)(wrow + 32 + g * 8 + 4);
        float ps = 0.f;
#pragma unroll
        for (int j = 0; j < 4; ++j) {
            ps = fmaf(w0a[j], w0a[j], ps); ps = fmaf(w0b[j], w0b[j], ps);
            ps = fmaf(w1a[j], w1a[j], ps); ps = fmaf(w1b[j], w1b[j], ps);
        }
        i32x4 p0, p1;
        p0[0] = cvt_pk_bf16(w0a[0], w0a[1]); p0[1] = cvt_pk_bf16(w0a[2], w0a[3]);
        p0[2] = cvt_pk_bf16(w0b[0], w0b[1]); p0[3] = cvt_pk_bf16(w0b[2], w0b[3]);
        p1[0] = cvt_pk_bf16(w1a[0], w1a[1]); p1[1] = cvt_pk_bf16(w1a[2], w1a[3]);
        p1[2] = cvt_pk_bf16(w1b[0], w1b[1]); p1[3] = cvt_pk_bf16(w1b[2], w1b[3]);
        af[kt][0] = __builtin_bit_cast(bf16x8, p0);
        af[kt][1] = __builtin_bit_cast(bf16x8, p1);
        float s = ps + __shfl_xor(ps, 16);
        s += __shfl_xor(s, 32);
        f32x4 w4;
#pragma unroll
        for (int r = 0; r < 4; ++r) w4[r] = __shfl(s, g * 4 + r) + 2.0f;
        ww4[kt] = w4;
    }

    // ---- stage group-0 x: pack bf16(-2x), x^2, one 16B swizzled write ----
    {
        i32x4 pk;
#pragma unroll
        for (int j = 0; j < 4; ++j) {
            const float a = xv0[2 * j], bq = xv0[2 * j + 1];
            contrib = fmaf(a, a, contrib); contrib = fmaf(bq, bq, contrib);
            pk[j] = cvt_pk_bf16(-2.0f * a, -2.0f * bq);
        }
        *(i32x4*)(xl[0] + pos * 128 + swx) = pk;
    }
    __syncthreads();                               // xl[0] staged

    const int swa = (g ^ (c & 7)) << 4;            // f=0 phys chunk byte
    const int swb = (((4 + g) ^ (c & 7))) << 4;    // f=1 phys chunk byte
    const int p   = tid >> 3;                      // store: position 0..63
    const int q   = tid & 7;                       // store: dim octant

#pragma unroll
    for (int grp = 0; grp < 2; ++grp) {
        // issue next group's x-loads (latency hides under this k-loop)
        float xv1[8];
        if (grp == 0) {
#pragma unroll
            for (int j = 0; j < 8; ++j) xv1[j] = xpb[(ch * 8 + j) * HW + 64];
        }

        // ---- k-loop: 4 pos-tiles x (4 k-tiles x 2 MFMA) per wave ----
#pragma unroll
        for (int pt = 0; pt < 4; ++pt) {
            const char* xrow = xl[grp] + (pt * 16 + c) * 128;
            const bf16x8 b0 = *(const bf16x8*)(xrow + swa);
            const bf16x8 b1 = *(const bf16x8*)(xrow + swb);
            unsigned int best = 0xFFFFFFFFu;
#pragma unroll
            for (int kt = 0; kt < 4; ++kt) {
                f32x4 acc = __builtin_amdgcn_mfma_f32_16x16x32_bf16(af[kt][0], b0, ww4[kt], 0, 0, 0);
                acc       = __builtin_amdgcn_mfma_f32_16x16x32_bf16(af[kt][1], b1, acc, 0, 0, 0);
                const unsigned int kb = (unsigned int)(kw + kt * 16 + g * 4);
                const unsigned int t0 = (__builtin_bit_cast(unsigned int, acc[0]) & 0xFFFFFE00u) | (kb + 0);
                const unsigned int t1 = (__builtin_bit_cast(unsigned int, acc[1]) & 0xFFFFFE00u) | (kb + 1);
                const unsigned int t2 = (__builtin_bit_cast(unsigned int, acc[2]) & 0xFFFFFE00u) | (kb + 2);
                const unsigned int t3 = (__builtin_bit_cast(unsigned int, acc[3]) & 0xFFFFFE00u) | (kb + 3);
                best = umin32(umin32(umin32(t0, t1), umin32(t2, t3)), best);
            }
            unsigned int o;
            o = __shfl_xor(best, 16); best = umin32(best, o);
            o = __shfl_xor(best, 32); best = umin32(best, o);
            if (l < 16) atomicMin(&bestmin[grp][pt * 16 + c], best);
        }

        // stage next group's x into the other buffer (loads have arrived)
        if (grp == 0) {
            i32x4 pk;
#pragma unroll
            for (int j = 0; j < 4; ++j) {
                const float a = xv1[2 * j], bq = xv1[2 * j + 1];
                contrib = fmaf(a, a, contrib); contrib = fmaf(bq, bq, contrib);
                pk[j] = cvt_pk_bf16(-2.0f * a, -2.0f * bq);
            }
            *(i32x4*)(xl[1] + pos * 128 + swx) = pk;
        }
        __syncthreads();                           // bestmin[grp] final; xl[1] staged

        // ---- gather winning row (32B contiguous per thread), loss, store ----
        const int k = (int)(bestmin[grp][p] & 511u);
        const f32x4* er = (const f32x4*)(emb + k * 64 + q * 8);
        const f32x4 q0 = er[0], q1 = er[1];

        if (tid < 64)
            contrib += __builtin_bit_cast(float, bestmin[grp][tid] & 0xFFFFFE00u) - 2.0f;

        float* obase = out + (size_t)b * (DIM * HW) + hw0 + grp * 64 + p;
#pragma unroll
        for (int j = 0; j < 4; ++j) obase[(q * 8 + j)     * HW] = q0[j];
#pragma unroll
        for (int j = 0; j < 4; ++j) obase[(q * 8 + 4 + j) * HW] = q1[j];
    }

    // ---- loss: wave reduce -> wsum -> one partial per block ----
#pragma unroll
    for (int off = 32; off; off >>= 1) contrib += __shfl_xor(contrib, off, 64);
    if (l == 0) wsum[wave] = contrib;
    __syncthreads();
    if (tid == 0) {
        float tot = 0.f;
#pragma unroll
        for (int i = 0; i < 8; ++i) tot += wsum[i];
        partial[blockIdx.x] = tot;                 // plain store, no atomic
    }
    // no trailing barrier: stores drain at endpgm
}

__global__ __launch_bounds__(512) void finalize_kernel(
    const float* __restrict__ partial, float* __restrict__ out) {
    const int tid = threadIdx.x;
    double s = (double)partial[tid];
#pragma unroll
    for (int off = 32; off; off >>= 1) s += __shfl_xor(s, off, 64);
    __shared__ double dsum[8];
    if ((tid & 63) == 0) dsum[tid >> 6] = s;
    __syncthreads();
    if (tid == 0) {
        double tot = 0.0;
#pragma unroll
        for (int i = 0; i < 8; ++i) tot += dsum[i];
        out[TOTAL] = (float)(1.25 * tot / (double)TOTAL);
    }
}

extern "C" void kernel_launch(void* const* d_in, const int* in_sizes, int n_in,
                              void* d_out, int out_size, void* d_ws, size_t ws_size,
                              hipStream_t stream) {
    const float* latents = (const float*)d_in[0];
    const float* emb     = (const float*)d_in[1];
    float* out = (float*)d_out;
    float* partial = (float*)d_ws;

    fused_vq_kernel<<<FUSED_BLOCKS, 512, 0, stream>>>(latents, emb, out, partial);
    finalize_kernel<<<1, 512, 0, stream>>>(partial, out);
}